// Round 7
// baseline (2033.549 us; speedup 1.0000x reference)
//
#include <hip/hip_runtime.h>
#include <cmath>

// ---------------- problem constants ----------------
#define S_   512
#define Z_   514            // SD + H
#define WUC  516            // WU_w cols: [x(2) | u(2) | h(512)]

// output float offsets
#define OUT_ZF   67371008   // B*S*Z
#define OUT_CZF  67502592   // + B*Z
#define OUT_COEF 67634176   // + B*Z

// ---------------- workspace layout ----------------
// img: [slot(4)][pair(8)][half(2)] x 16KB f16 half-image [16 rows][512 units].
// 1MB total, memset 0xFF at launch = f16 NaN sentinel (h is always finite).
#define IMGH(slot, half) (img + (((size_t)(slot) * 8 + p) * 2 + (half)) * 16384)

typedef __attribute__((ext_vector_type(4))) float f32x4;
typedef __attribute__((ext_vector_type(4))) unsigned u32x4;
typedef __attribute__((ext_vector_type(8))) _Float16 f16x8;

__device__ __forceinline__ f32x4 MF16(f16x8 a, f16x8 b, f32x4 c) {
  return __builtin_amdgcn_mfma_f32_16x16x32_f16(a, b, c, 0, 0, 0);
}
// system-scope (sc0 sc1) coherent ops — round-2/4/6-proven encoding
__device__ __forceinline__ u32x4 ld16c(const void* p) {
  u32x4 r;
  asm volatile("global_load_dwordx4 %0, %1, off sc0 sc1" : "=v"(r) : "v"(p));
  return r;
}
__device__ __forceinline__ void st16c(void* p, u32x4 v) {
  asm volatile("global_store_dwordx4 %0, %1, off sc0 sc1" :: "v"(p), "v"(v) : "memory");
}
__device__ __forceinline__ void st4c(void* p, unsigned v) {
  asm volatile("global_store_dword %0, %1, off sc0 sc1" :: "v"(p), "v"(v) : "memory");
}
// chunk ready: no dword still holds the poison pattern in its low half
__device__ __forceinline__ bool rdy(u32x4 v) {
  unsigned b = (unsigned)((v[0] & 0xFFFFu) == 0xFFFFu) |
               (unsigned)((v[1] & 0xFFFFu) == 0xFFFFu) |
               (unsigned)((v[2] & 0xFFFFu) == 0xFFFFu) |
               (unsigned)((v[3] & 0xFFFFu) == 0xFFFFu);
  return b == 0u;
}
__device__ __forceinline__ float sigm(float x)  { return 1.f / (1.f + __expf(-x)); }
__device__ __forceinline__ float ftanh(float x) { return 2.f / (1.f + __expf(-2.f * x)) - 1.f; }

// spin with pre-issued loads; rule-#18 fence after every vmcnt drain
#define SPIN(P0, P1, BASE)                                                   \
  {                                                                          \
    asm volatile("s_waitcnt vmcnt(0)" ::: "memory");                         \
    __builtin_amdgcn_sched_barrier(0);                                       \
    bool ok0 = rdy(P0), ok1 = rdy(P1);                                       \
    while (!(ok0 && ok1)) {                                                  \
      __builtin_amdgcn_s_sleep(1);                                           \
      if (!ok0) P0 = ld16c(BASE);                                            \
      if (!ok1) P1 = ld16c((BASE) + 64);                                     \
      asm volatile("s_waitcnt vmcnt(0)" ::: "memory");                       \
      __builtin_amdgcn_sched_barrier(0);                                     \
      ok0 = rdy(P0); ok1 = rdy(P1);                                          \
    }                                                                        \
    __builtin_amdgcn_sched_barrier(0);                                       \
  }

// one half-group phase: spin, GEMM, pointwise, publish, prefetch other half
#define PHASE(HALF, P0, P1, NP0, NP1, NHALF, SR, SW, SP, SN, GBR,            \
              PX0, PX1, CS, U0P, TAUP, HV, T)                                \
  {                                                                          \
    const char* baseR_ = IMGH(SR, HALF) + fragbase;                          \
    SPIN(P0, P1, baseR_);                                                    \
    float u0v = 0.f, u1v = 0.f, tv = 0.f;                                    \
    if (tid < 256) {                                                         \
      u0v = rnn[((size_t)(GBR) * S_ + (T)) * 2 + 0];                         \
      u1v = rnn[((size_t)(GBR) * S_ + (T)) * 2 + 1];                         \
      tv  = tau[(size_t)(GBR) * S_ + (T)];                                   \
    }                                                                        \
    f32x4 a0={0,0,0,0}, a1={0,0,0,0}, a2={0,0,0,0}, a3={0,0,0,0}, a4={0,0,0,0};\
    {                                                                        \
      f16x8 ah0 = __builtin_bit_cast(f16x8, P0);                             \
      f16x8 ah1 = __builtin_bit_cast(f16x8, P1);                             \
      a0 = MF16(ah0, bHf[0][0], a0); a0 = MF16(ah0, bLf[0][0], a0);          \
      a1 = MF16(ah0, bHf[0][1], a1); a1 = MF16(ah0, bLf[0][1], a1);          \
      a2 = MF16(ah0, bHf[0][2], a2); a2 = MF16(ah0, bLf[0][2], a2);          \
      a3 = MF16(ah0, bHf[0][3], a3); a3 = MF16(ah0, bLf[0][3], a3);          \
      a4 = MF16(ah0, bHf[0][4], a4); a4 = MF16(ah0, bLf[0][4], a4);          \
      a0 = MF16(ah1, bHf[1][0], a0); a0 = MF16(ah1, bLf[1][0], a0);          \
      a1 = MF16(ah1, bHf[1][1], a1); a1 = MF16(ah1, bLf[1][1], a1);          \
      a2 = MF16(ah1, bHf[1][2], a2); a2 = MF16(ah1, bLf[1][2], a2);          \
      a3 = MF16(ah1, bHf[1][3], a3); a3 = MF16(ah1, bLf[1][3], a3);          \
      a4 = MF16(ah1, bHf[1][4], a4); a4 = MF16(ah1, bLf[1][4], a4);          \
    }                                                                        \
    {                                                                        \
      const int Rb_ = kq * 16 + lq * 4;                                      \
      _Pragma("unroll")                                                      \
      for (int r_ = 0; r_ < 4; ++r_) {                                       \
        const int row_ = Rb_ + r_;                                           \
        float* cp_ = cscr + row_ * 112;                                      \
        const int xb_ = ((row_ >> 2) & 1) << 4;                              \
        cp_[(0  ^ xb_) + ln15] = a0[r_];                                     \
        cp_[(16 ^ xb_) + ln15] = a1[r_];                                     \
        cp_[(32 ^ xb_) + ln15] = a2[r_];                                     \
        cp_[(48 ^ xb_) + ln15] = a3[r_];                                     \
        cp_[(64 ^ xb_) + ln15] = a4[r_];                                     \
      }                                                                      \
    }                                                                        \
    __syncthreads(); /* B1: LDS write->read */                               \
    if (tid < 256) {                                                         \
      float g0=0,g1=0,g2=0,g3=0,d0=0,d1=0,d2=0,d3=0;                         \
      _Pragma("unroll")                                                      \
      for (int q_ = 0; q_ < 8; ++q_) {                                       \
        const int row_ = q_ * 16 + bb;                                       \
        const float* cp_ = cscr + row_ * 112;                                \
        const int xb_ = ((row_ >> 2) & 1) << 4;                              \
        g0 += cp_[(0  ^ xb_) + jj]; g1 += cp_[(16 ^ xb_) + jj];              \
        g2 += cp_[(32 ^ xb_) + jj]; g3 += cp_[(48 ^ xb_) + jj];              \
        const f32x4 dv_ = *(const f32x4*)(cp_ + (64 ^ xb_));                 \
        d0 += dv_[0]; d1 += dv_[1]; d2 += dv_[2]; d3 += dv_[3];              \
      }                                                                      \
      if ((T) > 0) {                                                         \
        const float al0_ = sigm(d0 + pab0), al1_ = sigm(d1 + pab1);          \
        const float wh0_ = d2 + pwb0, wh1_ = d3 + pwb1;                      \
        const float xm0_ = PX0 + TAUP * (pA00*PX0 + pA01*PX1 + pB0*U0P);     \
        const float xm1_ = PX1 + TAUP * (pA10*PX0 + pA11*PX1 + pB1*U0P);     \
        PX0 = al0_*xm0_ + (1.f - al0_)*wh0_;                                 \
        PX1 = al1_*xm1_ + (1.f - al1_)*wh1_;                                 \
        if (gg == 0 && jj == 0) {                                            \
          const size_t ob_ = ((size_t)(GBR) * S_ + ((T) - 1)) * Z_;          \
          __builtin_nontemporal_store(PX0, out + ob_ + 0);                   \
          __builtin_nontemporal_store(PX1, out + ob_ + 1);                   \
          const size_t cb_ = OUT_COEF + ((size_t)(GBR) * S_ + ((T) - 1)) * 2;\
          __builtin_nontemporal_store(al0_, out + cb_ + 0);                  \
          __builtin_nontemporal_store(al1_, out + cb_ + 1);                  \
        }                                                                    \
      }                                                                      \
      g0 += gbL[0][jj] + PX0*gwL[0][jj][0] + PX1*gwL[0][jj][1] + u0v*gwL[0][jj][2] + u1v*gwL[0][jj][3]; \
      g1 += gbL[1][jj] + PX0*gwL[1][jj][0] + PX1*gwL[1][jj][1] + u0v*gwL[1][jj][2] + u1v*gwL[1][jj][3]; \
      g2 += gbL[2][jj] + PX0*gwL[2][jj][0] + PX1*gwL[2][jj][1] + u0v*gwL[2][jj][2] + u1v*gwL[2][jj][3]; \
      g3 += gbL[3][jj] + PX0*gwL[3][jj][0] + PX1*gwL[3][jj][1] + u0v*gwL[3][jj][2] + u1v*gwL[3][jj][3]; \
      const float ci_ = sigm(g0), cf_ = sigm(g1), co_ = sigm(g3);            \
      CS = cf_ * CS + ci_ * ftanh(g2);                                       \
      HV = co_ * ftanh(CS);                                                  \
      U0P = u0v; TAUP = tv;                                                  \
      {                                                                      \
        unsigned hz_ = (unsigned)__builtin_bit_cast(unsigned short, (_Float16)HV); \
        unsigned ph_ = (unsigned)__shfl_xor((int)hz_, 1);                    \
        if ((jj & 1) == 0)                                                   \
          st4c(IMGH(SW, HALF) + bb * 1024 + (j0 + jj) * 2, hz_ | (ph_ << 16)); \
      }                                                                      \
      __builtin_nontemporal_store(HV, out + ((size_t)(GBR)*S_ + (T))*Z_ + 2 + j0 + jj); \
    }                                                                        \
    /* all waves: prefetch the next phase's fragments (speculative) */       \
    {                                                                        \
      const char* nb_ = IMGH(SN, NHALF) + fragbase;                          \
      NP0 = ld16c(nb_); NP1 = ld16c(nb_ + 64);                               \
    }                                                                        \
    /* wave 7: re-poison this half's slice of slot SP (dead h(T-2)) */       \
    if (wv == 7 && lane < 32) {                                              \
      u32x4 poison_ = {~0u, ~0u, ~0u, ~0u};                                  \
      st16c(IMGH(SP, HALF) + (lane >> 1) * 1024 + (j0 + (lane & 1) * 8) * 2, \
            poison_);                                                        \
    }                                                                        \
    /* B2: raw barrier — no vmcnt drain; acks retire in the next spin */     \
    __builtin_amdgcn_sched_barrier(0);                                       \
    __builtin_amdgcn_s_barrier();                                            \
    __builtin_amdgcn_sched_barrier(0);                                       \
  }

// grid: 256 blocks = pair(8) x gg(32); block: 512 threads = 8 waves (one per K-64)
__global__ __launch_bounds__(512, 2) void lstm_persist(
    const float* __restrict__ rnn, const float* __restrict__ tau,
    const float* __restrict__ z0,  const float* __restrict__ c0,
    const float* __restrict__ wuw, const float* __restrict__ wub,
    const float* __restrict__ awp, const float* __restrict__ abp,
    const float* __restrict__ whw, const float* __restrict__ whb,
    const float* __restrict__ Amat, const float* __restrict__ Bmat,
    float* __restrict__ out, char* __restrict__ img)
{
  __shared__ float cscr[128 * 112];      // 57 KB swizzled partials (reused A/B)
  __shared__ float gwL[4][16][4];
  __shared__ float gbL[4][16];

  const int tid = threadIdx.x;
  const int blk = blockIdx.x;
  const int p   = blk & 7;          // pair -> rows [p*32, p*32+32); A=first 16, B=last 16
  const int gg  = blk >> 3;
  const int j0  = gg * 16;
  const int lane = tid & 63;
  const int wv   = tid >> 6;        // wave = kq (K-chunk of 64)
  const int kq   = wv;
  const int ln15 = lane & 15;
  const int lq   = lane >> 4;
  const int bb   = (tid >> 4) & 15; // pointwise row within half (tid<256)
  const int jj   = tid & 15;

  // ---------------- prologue: weights -> registers (split f16) ----------------
  f16x8 bHf[2][5], bLf[2][5];
#pragma unroll
  for (int s = 0; s < 2; ++s) {
    const int kbase = kq * 64 + s * 32 + lq * 8;
#pragma unroll
    for (int n = 0; n < 4; ++n) {
      const float* wp = wuw + (size_t)(n * 512 + j0 + ln15) * WUC + 4 + kbase;
      f16x8 vh, vl;
#pragma unroll
      for (int e = 0; e < 8; ++e) {
        float w = wp[e];
        _Float16 hi = (_Float16)w;
        vh[e] = hi;
        vl[e] = (_Float16)(w - (float)hi);
      }
      bHf[s][n] = vh; bLf[s][n] = vl;
    }
    {
      f16x8 vh, vl;
#pragma unroll
      for (int e = 0; e < 8; ++e) {   // n=4: [alpha_w ; Wh_w ; zeros] tile
        int k = kbase + e;
        float w = 0.f;
        if (ln15 < 2)      w = awp[ln15 * 512 + k];
        else if (ln15 < 4) w = whw[(ln15 - 2) * 512 + k];
        _Float16 hi = (_Float16)w;
        vh[e] = hi;
        vl[e] = (_Float16)(w - (float)hi);
      }
      bHf[s][4] = vh; bLf[s][4] = vl;
    }
  }
  const float pA00 = Amat[0], pA01 = Amat[1], pA10 = Amat[2], pA11 = Amat[3];
  const float pB0 = Bmat[0], pB1 = Bmat[1];
  const float pab0 = abp[0], pab1 = abp[1], pwb0 = whb[0], pwb1 = whb[1];
  if (tid < 64) {
    const int n = tid >> 4, j = tid & 15;
    const int r = n * 512 + j0 + j;
    gbL[n][j] = wub[r];
    const float* wr = wuw + (size_t)r * WUC;
    gwL[n][j][0] = wr[0]; gwL[n][j][1] = wr[1];
    gwL[n][j][2] = wr[2]; gwL[n][j][3] = wr[3];
  }
  // per-half states (meaningful for tid<256; each thread owns rows gbA and gbB)
  const int gbA = p * 32 + bb;
  const int gbB = p * 32 + 16 + bb;
  float pxA0 = z0[(size_t)gbA * Z_ + 0], pxA1 = z0[(size_t)gbA * Z_ + 1];
  float pxB0 = z0[(size_t)gbB * Z_ + 0], pxB1 = z0[(size_t)gbB * Z_ + 1];
  float cA = c0[(size_t)gbA * Z_ + 2 + j0 + jj];
  float cB = c0[(size_t)gbB * Z_ + 2 + j0 + jj];
  float u0pA = 0.f, taupA = 0.f, hA = 0.f;
  float u0pB = 0.f, taupB = 0.f, hB = 0.f;

  // publish z0 h into slot 3 (both halves; 512 threads cover half = tid>>8)
  {
    const int half = tid >> 8, bz = (tid >> 4) & 15;
    const int row = p * 32 + half * 16 + bz;
    float hv = z0[(size_t)row * Z_ + 2 + j0 + jj];
    unsigned hz = (unsigned)__builtin_bit_cast(unsigned short, (_Float16)hv);
    unsigned ph = (unsigned)__shfl_xor((int)hz, 1);
    if ((jj & 1) == 0)
      st4c(IMGH(3, half) + bz * 1024 + (j0 + jj) * 2, hz | (ph << 16));
  }

  const int fragbase = ln15 * 1024 + kq * 128 + lq * 16;
  // prefetch phase-A fragments for t=0 (slot 3, half 0)
  u32x4 PA0, PA1, PB0, PB1;
  { const char* b = IMGH(3, 0) + fragbase; PA0 = ld16c(b); PA1 = ld16c(b + 64); }
  __syncthreads();

  // ---------------- main loop: A phase then B phase per step ----------------
  for (int t = 0; t < S_; ++t) {
    const int sR = (t + 3) & 3, sW = t & 3, sP = (t + 2) & 3;
    // A phase: reads h_A(t-1); prefetches B fragments (slot sR, half 1)
    PHASE(0, PA0, PA1, PB0, PB1, 1, sR, sW, sP, sR, gbA,
          pxA0, pxA1, cA, u0pA, taupA, hA, t)
    // B phase: reads h_B(t-1); prefetches A fragments for t+1 (slot sW, half 0)
    PHASE(1, PB0, PB1, PA0, PA1, 0, sR, sW, sP, sW, gbB,
          pxB0, pxB1, cB, u0pB, taupB, hB, t)
  }

  // ---------------- tail: dots over h(511) -> alpha/x(511) ----------------
  // PA holds h_A(511) (prefetched in B phase t=511: slot 3, half 0).
  { const char* b = IMGH(3, 1) + fragbase; PB0 = ld16c(b); PB1 = ld16c(b + 64); }
  {
    const char* baseRA = IMGH(3, 0) + fragbase;
    SPIN(PA0, PA1, baseRA);
    f32x4 a4 = {0,0,0,0};
    f16x8 ah0 = __builtin_bit_cast(f16x8, PA0);
    f16x8 ah1 = __builtin_bit_cast(f16x8, PA1);
    a4 = MF16(ah0, bHf[0][4], a4); a4 = MF16(ah0, bLf[0][4], a4);
    a4 = MF16(ah1, bHf[1][4], a4); a4 = MF16(ah1, bLf[1][4], a4);
    const int Rb = kq * 16 + lq * 4;
#pragma unroll
    for (int r = 0; r < 4; ++r) cscr[(Rb + r) * 112 + 64 + ln15] = a4[r];
  }
  {
    const char* baseRB = IMGH(3, 1) + fragbase;
    SPIN(PB0, PB1, baseRB);
    f32x4 a4 = {0,0,0,0};
    f16x8 ah0 = __builtin_bit_cast(f16x8, PB0);
    f16x8 ah1 = __builtin_bit_cast(f16x8, PB1);
    a4 = MF16(ah0, bHf[0][4], a4); a4 = MF16(ah0, bLf[0][4], a4);
    a4 = MF16(ah1, bHf[1][4], a4); a4 = MF16(ah1, bLf[1][4], a4);
    const int Rb = kq * 16 + lq * 4;
#pragma unroll
    for (int r = 0; r < 4; ++r) cscr[(Rb + r) * 112 + 80 + ln15] = a4[r];
  }
  __syncthreads();
  if (tid < 256) {
    float dA0=0,dA1=0,dA2=0,dA3=0, dB0=0,dB1=0,dB2=0,dB3=0;
#pragma unroll
    for (int q = 0; q < 8; ++q) {
      const float* cp = cscr + (q * 16 + bb) * 112;
      const f32x4 va = *(const f32x4*)(cp + 64);
      const f32x4 vb = *(const f32x4*)(cp + 80);
      dA0 += va[0]; dA1 += va[1]; dA2 += va[2]; dA3 += va[3];
      dB0 += vb[0]; dB1 += vb[1]; dB2 += vb[2]; dB3 += vb[3];
    }
    const float alA0 = sigm(dA0 + pab0), alA1 = sigm(dA1 + pab1);
    const float alB0 = sigm(dB0 + pab0), alB1 = sigm(dB1 + pab1);
    const float xmA0 = pxA0 + taupA * (pA00*pxA0 + pA01*pxA1 + pB0*u0pA);
    const float xmA1 = pxA1 + taupA * (pA10*pxA0 + pA11*pxA1 + pB1*u0pA);
    const float xmB0 = pxB0 + taupB * (pA00*pxB0 + pA01*pxB1 + pB0*u0pB);
    const float xmB1 = pxB1 + taupB * (pA10*pxB0 + pA11*pxB1 + pB1*u0pB);
    const float xA0 = alA0*xmA0 + (1.f-alA0)*(dA2 + pwb0);
    const float xA1 = alA1*xmA1 + (1.f-alA1)*(dA3 + pwb1);
    const float xB0 = alB0*xmB0 + (1.f-alB0)*(dB2 + pwb0);
    const float xB1 = alB1*xmB1 + (1.f-alB1)*(dB3 + pwb1);
    if (gg == 0 && jj == 0) {
      const size_t oa = ((size_t)gbA * S_ + 511) * Z_;
      const size_t ob = ((size_t)gbB * S_ + 511) * Z_;
      __builtin_nontemporal_store(xA0, out + oa + 0);
      __builtin_nontemporal_store(xA1, out + oa + 1);
      __builtin_nontemporal_store(xB0, out + ob + 0);
      __builtin_nontemporal_store(xB1, out + ob + 1);
      const size_t ca = OUT_COEF + ((size_t)gbA * S_ + 511) * 2;
      const size_t cb = OUT_COEF + ((size_t)gbB * S_ + 511) * 2;
      __builtin_nontemporal_store(alA0, out + ca + 0);
      __builtin_nontemporal_store(alA1, out + ca + 1);
      __builtin_nontemporal_store(alB0, out + cb + 0);
      __builtin_nontemporal_store(alB1, out + cb + 1);
      __builtin_nontemporal_store(xA0, out + OUT_ZF + (size_t)gbA * Z_ + 0);
      __builtin_nontemporal_store(xA1, out + OUT_ZF + (size_t)gbA * Z_ + 1);
      __builtin_nontemporal_store(xB0, out + OUT_ZF + (size_t)gbB * Z_ + 0);
      __builtin_nontemporal_store(xB1, out + OUT_ZF + (size_t)gbB * Z_ + 1);
      __builtin_nontemporal_store(c0[(size_t)gbA * Z_ + 0], out + OUT_CZF + (size_t)gbA * Z_ + 0);
      __builtin_nontemporal_store(c0[(size_t)gbA * Z_ + 1], out + OUT_CZF + (size_t)gbA * Z_ + 1);
      __builtin_nontemporal_store(c0[(size_t)gbB * Z_ + 0], out + OUT_CZF + (size_t)gbB * Z_ + 0);
      __builtin_nontemporal_store(c0[(size_t)gbB * Z_ + 1], out + OUT_CZF + (size_t)gbB * Z_ + 1);
    }
    __builtin_nontemporal_store(hA, out + OUT_ZF  + (size_t)gbA * Z_ + 2 + j0 + jj);
    __builtin_nontemporal_store(hB, out + OUT_ZF  + (size_t)gbB * Z_ + 2 + j0 + jj);
    __builtin_nontemporal_store(cA, out + OUT_CZF + (size_t)gbA * Z_ + 2 + j0 + jj);
    __builtin_nontemporal_store(cB, out + OUT_CZF + (size_t)gbB * Z_ + 2 + j0 + jj);
  }
}

extern "C" void kernel_launch(void* const* d_in, const int* in_sizes, int n_in,
                              void* d_out, int out_size, void* d_ws, size_t ws_size,
                              hipStream_t stream) {
  const float* rnn  = (const float*)d_in[0];
  const float* tauP = (const float*)d_in[1];
  const float* z0   = (const float*)d_in[2];
  const float* c0   = (const float*)d_in[3];
  const float* wuw  = (const float*)d_in[4];
  const float* wub  = (const float*)d_in[5];
  const float* awp  = (const float*)d_in[6];
  const float* abp  = (const float*)d_in[7];
  const float* whw  = (const float*)d_in[8];
  const float* whb  = (const float*)d_in[9];
  const float* Amat = (const float*)d_in[10];
  const float* Bmat = (const float*)d_in[11];
  float* out = (float*)d_out;
  char* img = (char*)d_ws;   // 1 MB: 4 slots x 8 pairs x 2 halves x 16KB

  // poison all image slots (f16 NaN sentinel) every call — captured in the graph
  hipMemsetAsync(d_ws, 0xFF, 4 * 8 * 2 * 16384, stream);
  (void)in_sizes; (void)n_in; (void)out_size; (void)ws_size;

  hipLaunchKernelGGL(lstm_persist, dim3(256), dim3(512), 0, stream,
                     rnn, tauP, z0, c0, wuw, wub, awp, abp, whw, whb, Amat, Bmat,
                     out, img);
}

// Round 8
// 1775.663 us; speedup vs baseline: 1.1452x; 1.1452x over previous
//
#include <hip/hip_runtime.h>
#include <cmath>

// ---------------- problem constants ----------------
#define S_   512
#define Z_   514            // SD + H
#define WUC  516            // WU_w cols: [x(2) | u(2) | h(512)]

// output float offsets
#define OUT_ZF   67371008   // B*S*Z
#define OUT_CZF  67502592   // + B*Z
#define OUT_COEF 67634176   // + B*Z

// ---------------- workspace layout (identical to round 6) ----------------
// img: [slot(4)][bg(8)] x 32KB f16 image [32 rows][512 units]; 1MB total.
// memset 0xFF at launch = f16 NaN sentinel (h is always finite).
#define IMG_BYTES 32768

typedef __attribute__((ext_vector_type(4))) float f32x4;
typedef __attribute__((ext_vector_type(4))) unsigned u32x4;
typedef __attribute__((ext_vector_type(8))) _Float16 f16x8;

__device__ __forceinline__ f32x4 MF16(f16x8 a, f16x8 b, f32x4 c) {
  return __builtin_amdgcn_mfma_f32_16x16x32_f16(a, b, c, 0, 0, 0);
}
// system-scope (sc0 sc1) coherent ops — round-2/4/6-proven encoding
__device__ __forceinline__ u32x4 ld16c(const void* p) {
  u32x4 r;
  asm volatile("global_load_dwordx4 %0, %1, off sc0 sc1" : "=v"(r) : "v"(p));
  return r;
}
__device__ __forceinline__ void st16c(void* p, u32x4 v) {
  asm volatile("global_store_dwordx4 %0, %1, off sc0 sc1" :: "v"(p), "v"(v) : "memory");
}
__device__ __forceinline__ void st4c(void* p, unsigned v) {
  asm volatile("global_store_dword %0, %1, off sc0 sc1" :: "v"(p), "v"(v) : "memory");
}
// chunk ready: no dword still holds the poison pattern in its low half
__device__ __forceinline__ bool rdy(u32x4 v) {
  unsigned b = (unsigned)((v[0] & 0xFFFFu) == 0xFFFFu) |
               (unsigned)((v[1] & 0xFFFFu) == 0xFFFFu) |
               (unsigned)((v[2] & 0xFFFFu) == 0xFFFFu) |
               (unsigned)((v[3] & 0xFFFFu) == 0xFFFFu);
  return b == 0u;
}
__device__ __forceinline__ float sigm(float x)  { return 1.f / (1.f + __expf(-x)); }
__device__ __forceinline__ float ftanh(float x) { return 2.f / (1.f + __expf(-2.f * x)) - 1.f; }

// self-validating spin on 4 contiguous 16B chunks (rule-#18 fence after drain)
#define SPIN4(P0, P1, P2, P3, BASE)                                          \
  {                                                                          \
    bool ok0 = false, ok1 = false, ok2 = false, ok3 = false;                 \
    for (;;) {                                                               \
      if (!ok0) P0 = ld16c((BASE));                                          \
      if (!ok1) P1 = ld16c((BASE) + 16);                                     \
      if (!ok2) P2 = ld16c((BASE) + 32);                                     \
      if (!ok3) P3 = ld16c((BASE) + 48);                                     \
      asm volatile("s_waitcnt vmcnt(0)" ::: "memory");                       \
      __builtin_amdgcn_sched_barrier(0);                                     \
      ok0 = rdy(P0); ok1 = rdy(P1); ok2 = rdy(P2); ok3 = rdy(P3);            \
      if (ok0 && ok1 && ok2 && ok3) break;                                   \
      __builtin_amdgcn_s_sleep(1);                                           \
    }                                                                        \
    __builtin_amdgcn_sched_barrier(0);                                       \
  }

// grid: 256 blocks = bg(8) x gg(32); block: 512 threads = 8 waves = (m 2) x (gate 4)
__global__ __launch_bounds__(512, 2) void lstm_persist(
    const float* __restrict__ rnn, const float* __restrict__ tau,
    const float* __restrict__ z0,  const float* __restrict__ c0,
    const float* __restrict__ wuw, const float* __restrict__ wub,
    const float* __restrict__ awp, const float* __restrict__ abp,
    const float* __restrict__ whw, const float* __restrict__ whb,
    const float* __restrict__ Amat, const float* __restrict__ Bmat,
    float* __restrict__ out, char* __restrict__ img)
{
  __shared__ __align__(16) char  hTile[32768];     // h(t-1) f16 [32][512], swizzled
  __shared__ __align__(16) float gscr[4][32][17];  // [gate][row][unit], stride-17
  __shared__ __align__(16) float dscr[2][4][16][4];// [m][kpart][row][4 dot cols]
  __shared__ float gwL[4][16][4];
  __shared__ float gbL[4][16];

  const int tid  = threadIdx.x;
  const int blk  = blockIdx.x;
  const int bg   = blk & 7;
  const int gg   = blk >> 3;
  const int j0   = gg * 16;
  const int lane = tid & 63;
  const int wv   = tid >> 6;
  const int m    = wv >> 2;        // M half: rows [m*16, m*16+16)
  const int gid  = wv & 3;         // gate index (i,f,g,o)
  const int ln15 = lane & 15;
  const int lq   = lane >> 4;
  const int bb   = tid >> 4;       // pointwise row 0..31
  const int jj   = tid & 15;       // pointwise unit
  const int gb   = bg * 32 + bb;

  // ---------------- prologue: weights -> registers (split f16) ----------------
  // wave (m,gid): full-K B-frags for its gate tile (16 units x K=512)
  f16x8 wHr[16], wLr[16];
#pragma unroll
  for (int k = 0; k < 16; ++k) {
    const float* wp = wuw + (size_t)(gid * 512 + j0 + ln15) * WUC + 4 + k * 32 + lq * 8;
    f16x8 vh, vl;
#pragma unroll
    for (int e = 0; e < 8; ++e) {
      float w = wp[e];
      _Float16 hi = (_Float16)w;
      vh[e] = hi; vl[e] = (_Float16)(w - (float)hi);
    }
    wHr[k] = vh; wLr[k] = vl;
  }
  // dots tile B-frags: K-quarter gid (cols 0,1 = alpha_w; 2,3 = Wh_w)
  f16x8 dHr[4], dLr[4];
#pragma unroll
  for (int i = 0; i < 4; ++i) {
    const int kg = (gid * 4 + i) * 32 + lq * 8;
    f16x8 vh, vl;
#pragma unroll
    for (int e = 0; e < 8; ++e) {
      int k = kg + e;
      float w = 0.f;
      if (ln15 < 2)      w = awp[ln15 * 512 + k];
      else if (ln15 < 4) w = whw[(ln15 - 2) * 512 + k];
      _Float16 hi = (_Float16)w;
      vh[e] = hi; vl[e] = (_Float16)(w - (float)hi);
    }
    dHr[i] = vh; dLr[i] = vl;
  }
  const float pA00 = Amat[0], pA01 = Amat[1], pA10 = Amat[2], pA11 = Amat[3];
  const float pB0 = Bmat[0], pB1 = Bmat[1];
  const float pab0 = abp[0], pab1 = abp[1], pwb0 = whb[0], pwb1 = whb[1];
  if (tid < 64) {
    const int n = tid >> 4, j = tid & 15;
    const int r = n * 512 + j0 + j;
    gbL[n][j] = wub[r];
    const float* wr = wuw + (size_t)r * WUC;
    gwL[n][j][0] = wr[0]; gwL[n][j][1] = wr[1];
    gwL[n][j][2] = wr[2]; gwL[n][j][3] = wr[3];
  }
  float px0 = z0[(size_t)gb * Z_ + 0], px1 = z0[(size_t)gb * Z_ + 1];
  float c_state = c0[(size_t)gb * Z_ + 2 + j0 + jj];
  float u0_prev = 0.f, tau_prev = 0.f, hval = 0.f;
  float alc0 = 0.f, alc1 = 0.f;

  // publish z0 h-slice into slot 3 (pair-packed, fire-and-forget) — round 6
  {
    float hv = z0[(size_t)gb * Z_ + 2 + j0 + jj];
    unsigned hz = (unsigned)__builtin_bit_cast(unsigned short, (_Float16)hv);
    unsigned ph = (unsigned)__shfl_xor((int)hz, 1);
    if ((jj & 1) == 0)
      st4c(img + (size_t)(3 * 8 + bg) * IMG_BYTES + bb * 1024 + (j0 + jj) * 2,
           hz | (ph << 16));
  }
  __syncthreads();

  // spin slice: wave wv owns image rows [wv*4, wv*4+4); lane -> (row, 64B col chunk)
  const int srow   = wv * 4 + lq;
  const int scolb  = ln15 * 64;
  const int spinoff = srow * 1024 + scolb;
  const int ssw    = (srow & 7) << 4;    // LDS XOR swizzle (G4 / T2)
  // GEMM A-frag coords: row = m*16+ln15, k-chunk col = k*64 + lq*16 bytes
  const int rowa  = m * 16 + ln15;
  const int aw    = (rowa & 7) << 4;
  const int abase = rowa * 1024;
  const int mloc = bb >> 4, rloc = bb & 15;

  // ---------------- main loop ----------------
  for (int t = 0; t < S_; ++t) {
    const float u0v = rnn[((size_t)gb * S_ + t) * 2 + 0];
    const float u1v = rnn[((size_t)gb * S_ + t) * 2 + 1];
    const float tv  = tau[(size_t)gb * S_ + t];

    // deferred harness stores — acks complete in the spin shadow
    if (t >= 1)
      __builtin_nontemporal_store(hval, out + ((size_t)gb * S_ + (t - 1)) * Z_ + 2 + j0 + jj);
    if (t >= 2 && gg == 0 && jj == 0) {
      const size_t ob = ((size_t)gb * S_ + (t - 2)) * Z_;
      __builtin_nontemporal_store(px0, out + ob + 0);
      __builtin_nontemporal_store(px1, out + ob + 1);
      const size_t cb = OUT_COEF + ((size_t)gb * S_ + (t - 2)) * 2;
      __builtin_nontemporal_store(alc0, out + cb + 0);
      __builtin_nontemporal_store(alc1, out + cb + 1);
    }

    // spin on this wave's 4-row slice of slot (t-1)&3; the poll IS the data load
    const char* baseR = img + (size_t)(((t + 3) & 3) * 8 + bg) * IMG_BYTES + spinoff;
    u32x4 A0, A1, A2, A3;
    SPIN4(A0, A1, A2, A3, baseR);

    // stage into swizzled LDS h-tile
    *(u32x4*)(hTile + srow * 1024 + ((scolb +  0) ^ ssw)) = A0;
    *(u32x4*)(hTile + srow * 1024 + ((scolb + 16) ^ ssw)) = A1;
    *(u32x4*)(hTile + srow * 1024 + ((scolb + 32) ^ ssw)) = A2;
    *(u32x4*)(hTile + srow * 1024 + ((scolb + 48) ^ ssw)) = A3;
    __syncthreads();   // B0: stage -> GEMM

    // gate tile: full K=512, single accumulator (no cross-wave reduction)
    f32x4 a = {0, 0, 0, 0};
#pragma unroll
    for (int k = 0; k < 16; ++k) {
      u32x4 fr = *(const u32x4*)(hTile + abase + ((k * 64 + lq * 16) ^ aw));
      f16x8 ah = __builtin_bit_cast(f16x8, fr);
      a = MF16(ah, wHr[k], a);
      a = MF16(ah, wLr[k], a);
    }
    // dots tile: this wave's K-quarter
    f32x4 ad = {0, 0, 0, 0};
#pragma unroll
    for (int i = 0; i < 4; ++i) {
      u32x4 fr = *(const u32x4*)(hTile + abase + (((gid * 4 + i) * 64 + lq * 16) ^ aw));
      f16x8 ah = __builtin_bit_cast(f16x8, fr);
      ad = MF16(ah, dHr[i], ad);
      ad = MF16(ah, dLr[i], ad);
    }
#pragma unroll
    for (int r = 0; r < 4; ++r)
      gscr[gid][m * 16 + lq * 4 + r][ln15] = a[r];
    if (ln15 < 4) {
#pragma unroll
      for (int r = 0; r < 4; ++r)
        dscr[m][gid][lq * 4 + r][ln15] = ad[r];
    }
    __syncthreads();   // B1: GEMM -> pointwise

    // pointwise: direct 4-gate gather (no 8-deep reduce)
    float g0 = gscr[0][bb][jj], g1 = gscr[1][bb][jj];
    float g2 = gscr[2][bb][jj], g3 = gscr[3][bb][jj];
    float d0 = 0, d1 = 0, d2 = 0, d3 = 0;
#pragma unroll
    for (int kp = 0; kp < 4; ++kp) {
      const f32x4 dv = *(const f32x4*)dscr[mloc][kp][rloc];
      d0 += dv[0]; d1 += dv[1]; d2 += dv[2]; d3 += dv[3];
    }
    if (t > 0) {
      const float al0 = sigm(d0 + pab0), al1 = sigm(d1 + pab1);
      const float wh0 = d2 + pwb0, wh1 = d3 + pwb1;
      const float xm0 = px0 + tau_prev * (pA00 * px0 + pA01 * px1 + pB0 * u0_prev);
      const float xm1 = px1 + tau_prev * (pA10 * px0 + pA11 * px1 + pB1 * u0_prev);
      px0 = al0 * xm0 + (1.f - al0) * wh0;
      px1 = al1 * xm1 + (1.f - al1) * wh1;
      alc0 = al0; alc1 = al1;
    }
    g0 += gbL[0][jj] + px0 * gwL[0][jj][0] + px1 * gwL[0][jj][1] + u0v * gwL[0][jj][2] + u1v * gwL[0][jj][3];
    g1 += gbL[1][jj] + px0 * gwL[1][jj][0] + px1 * gwL[1][jj][1] + u0v * gwL[1][jj][2] + u1v * gwL[1][jj][3];
    g2 += gbL[2][jj] + px0 * gwL[2][jj][0] + px1 * gwL[2][jj][1] + u0v * gwL[2][jj][2] + u1v * gwL[2][jj][3];
    g3 += gbL[3][jj] + px0 * gwL[3][jj][0] + px1 * gwL[3][jj][1] + u0v * gwL[3][jj][2] + u1v * gwL[3][jj][3];
    const float ci = sigm(g0), cf = sigm(g1), co = sigm(g3);
    c_state = cf * c_state + ci * ftanh(g2);
    hval = co * ftanh(c_state);
    u0_prev = u0v; tau_prev = tv;

    // publish h(t) -> slot t&3 (pair-packed 4B, fire-and-forget)
    {
      unsigned hz = (unsigned)__builtin_bit_cast(unsigned short, (_Float16)hval);
      unsigned ph = (unsigned)__shfl_xor((int)hz, 1);
      if ((jj & 1) == 0)
        st4c(img + (size_t)((t & 3) * 8 + bg) * IMG_BYTES + bb * 1024 + (j0 + jj) * 2,
             hz | (ph << 16));
    }
    // wave 0 re-poisons this block's slice of slot (t+2)&3 (dead h(t-2)); its
    // visibility is guaranteed by wave 0's own vmcnt(0) in the next spin.
    if (wv == 0) {
      u32x4 poison = {~0u, ~0u, ~0u, ~0u};
      st16c(img + (size_t)(((t + 2) & 3) * 8 + bg) * IMG_BYTES
                + (lane >> 1) * 1024 + (j0 + (lane & 1) * 8) * 2, poison);
    }
    // B2: raw barrier — no vmcnt drain; store acks retire inside the next spin
    __builtin_amdgcn_sched_barrier(0);
    __builtin_amdgcn_s_barrier();
    __builtin_amdgcn_sched_barrier(0);
  }

  // ---------------- tail: pending stores + alpha/x for t = 511 ----------------
  __builtin_nontemporal_store(hval, out + ((size_t)gb * S_ + 511) * Z_ + 2 + j0 + jj);
  __builtin_nontemporal_store(hval,    out + OUT_ZF  + (size_t)gb * Z_ + 2 + j0 + jj);
  __builtin_nontemporal_store(c_state, out + OUT_CZF + (size_t)gb * Z_ + 2 + j0 + jj);
  if (gg == 0 && jj == 0) {
    const size_t ob = ((size_t)gb * S_ + 510) * Z_;
    __builtin_nontemporal_store(px0, out + ob + 0);
    __builtin_nontemporal_store(px1, out + ob + 1);
    const size_t cb = OUT_COEF + ((size_t)gb * S_ + 510) * 2;
    __builtin_nontemporal_store(alc0, out + cb + 0);
    __builtin_nontemporal_store(alc1, out + cb + 1);
  }

  // dots over h(511) (slot 3): spin slice -> stage -> 4-iter dots GEMM
  {
    const char* baseR = img + (size_t)(3 * 8 + bg) * IMG_BYTES + spinoff;
    u32x4 A0, A1, A2, A3;
    SPIN4(A0, A1, A2, A3, baseR);
    *(u32x4*)(hTile + srow * 1024 + ((scolb +  0) ^ ssw)) = A0;
    *(u32x4*)(hTile + srow * 1024 + ((scolb + 16) ^ ssw)) = A1;
    *(u32x4*)(hTile + srow * 1024 + ((scolb + 32) ^ ssw)) = A2;
    *(u32x4*)(hTile + srow * 1024 + ((scolb + 48) ^ ssw)) = A3;
    __syncthreads();
    f32x4 ad = {0, 0, 0, 0};
#pragma unroll
    for (int i = 0; i < 4; ++i) {
      u32x4 fr = *(const u32x4*)(hTile + abase + (((gid * 4 + i) * 64 + lq * 16) ^ aw));
      f16x8 ah = __builtin_bit_cast(f16x8, fr);
      ad = MF16(ah, dHr[i], ad);
      ad = MF16(ah, dLr[i], ad);
    }
    if (ln15 < 4) {
#pragma unroll
      for (int r = 0; r < 4; ++r)
        dscr[m][gid][lq * 4 + r][ln15] = ad[r];
    }
    __syncthreads();
  }
  {
    float d0 = 0, d1 = 0, d2 = 0, d3 = 0;
#pragma unroll
    for (int kp = 0; kp < 4; ++kp) {
      const f32x4 dv = *(const f32x4*)dscr[mloc][kp][rloc];
      d0 += dv[0]; d1 += dv[1]; d2 += dv[2]; d3 += dv[3];
    }
    const float al0 = sigm(d0 + pab0), al1 = sigm(d1 + pab1);
    const float wh0 = d2 + pwb0, wh1 = d3 + pwb1;
    const float xm0 = px0 + tau_prev * (pA00 * px0 + pA01 * px1 + pB0 * u0_prev);
    const float xm1 = px1 + tau_prev * (pA10 * px0 + pA11 * px1 + pB1 * u0_prev);
    const float xn0 = al0 * xm0 + (1.f - al0) * wh0;
    const float xn1 = al1 * xm1 + (1.f - al1) * wh1;
    if (gg == 0 && jj == 0) {
      const size_t ob = ((size_t)gb * S_ + 511) * Z_;
      __builtin_nontemporal_store(xn0, out + ob + 0);
      __builtin_nontemporal_store(xn1, out + ob + 1);
      const size_t cb = OUT_COEF + ((size_t)gb * S_ + 511) * 2;
      __builtin_nontemporal_store(al0, out + cb + 0);
      __builtin_nontemporal_store(al1, out + cb + 1);
      __builtin_nontemporal_store(xn0, out + OUT_ZF  + (size_t)gb * Z_ + 0);
      __builtin_nontemporal_store(xn1, out + OUT_ZF  + (size_t)gb * Z_ + 1);
      __builtin_nontemporal_store(c0[(size_t)gb * Z_ + 0], out + OUT_CZF + (size_t)gb * Z_ + 0);
      __builtin_nontemporal_store(c0[(size_t)gb * Z_ + 1], out + OUT_CZF + (size_t)gb * Z_ + 1);
    }
  }
}

extern "C" void kernel_launch(void* const* d_in, const int* in_sizes, int n_in,
                              void* d_out, int out_size, void* d_ws, size_t ws_size,
                              hipStream_t stream) {
  const float* rnn  = (const float*)d_in[0];
  const float* tauP = (const float*)d_in[1];
  const float* z0   = (const float*)d_in[2];
  const float* c0   = (const float*)d_in[3];
  const float* wuw  = (const float*)d_in[4];
  const float* wub  = (const float*)d_in[5];
  const float* awp  = (const float*)d_in[6];
  const float* abp  = (const float*)d_in[7];
  const float* whw  = (const float*)d_in[8];
  const float* whb  = (const float*)d_in[9];
  const float* Amat = (const float*)d_in[10];
  const float* Bmat = (const float*)d_in[11];
  float* out = (float*)d_out;
  char* img = (char*)d_ws;   // 1 MB: 4 slots x 8 bg x 32KB

  // poison all image slots (f16 NaN sentinel) every call — captured in the graph
  hipMemsetAsync(d_ws, 0xFF, 4 * 8 * IMG_BYTES, stream);
  (void)in_sizes; (void)n_in; (void)out_size; (void)ws_size;

  hipLaunchKernelGGL(lstm_persist, dim3(256), dim3(512), 0, stream,
                     rnn, tauP, z0, c0, wuw, wub, awp, abp, whw, whb, Amat, Bmat,
                     out, img);
}

// Round 9
// 1759.295 us; speedup vs baseline: 1.1559x; 1.0093x over previous
//
#include <hip/hip_runtime.h>
#include <cmath>

// ---------------- problem constants ----------------
#define S_   512
#define Z_   514            // SD + H
#define WUC  516            // WU_w cols: [x(2) | u(2) | h(512)]

// output float offsets
#define OUT_ZF   67371008   // B*S*Z
#define OUT_CZF  67502592   // + B*Z
#define OUT_COEF 67634176   // + B*Z

// ---------------- workspace layout ----------------
// img: [slot(4)][bg(8)] x 32KB f16 image [32 rows][512 units]; 1MB total.
// Launch-time memset 0xFF poisons everything (0xFFFF = f16 NaN sentinel;
// real h / z0-h are always finite, so sentinel is unambiguous).
#define IMG_BYTES 32768

typedef __attribute__((ext_vector_type(4))) float f32x4;
typedef __attribute__((ext_vector_type(4))) unsigned u32x4;
typedef __attribute__((ext_vector_type(8))) _Float16 f16x8;

__device__ __forceinline__ f32x4 MF16(f16x8 a, f16x8 b, f32x4 c) {
  return __builtin_amdgcn_mfma_f32_16x16x32_f16(a, b, c, 0, 0, 0);
}
// system-scope (sc0 sc1) coherent ops — round-2/4/6-proven encoding
__device__ __forceinline__ u32x4 ld16c(const void* p) {
  u32x4 r;
  asm volatile("global_load_dwordx4 %0, %1, off sc0 sc1" : "=v"(r) : "v"(p));
  return r;
}
__device__ __forceinline__ void st16c(void* p, u32x4 v) {
  asm volatile("global_store_dwordx4 %0, %1, off sc0 sc1" :: "v"(p), "v"(v) : "memory");
}
__device__ __forceinline__ void st4c(void* p, unsigned v) {
  asm volatile("global_store_dword %0, %1, off sc0 sc1" :: "v"(p), "v"(v) : "memory");
}
// chunk ready: no dword still holds the poison pattern in its low half
// (producer 4B stores are dword-atomic: each dword is all-poison or all-data)
__device__ __forceinline__ bool rdy(u32x4 v) {
  unsigned b = (unsigned)((v[0] & 0xFFFFu) == 0xFFFFu) |
               (unsigned)((v[1] & 0xFFFFu) == 0xFFFFu) |
               (unsigned)((v[2] & 0xFFFFu) == 0xFFFFu) |
               (unsigned)((v[3] & 0xFFFFu) == 0xFFFFu);
  return b == 0u;
}
// overflow-safe fast transcendentals (inf-graceful, no NaN paths)
__device__ __forceinline__ float sigm(float x)  { return 1.f / (1.f + __expf(-x)); }
__device__ __forceinline__ float ftanh(float x) { return 2.f / (1.f + __expf(-2.f * x)) - 1.f; }

// cscr swizzled index: stride 112 floats, XOR bit4 of col with (row>>2)&1.
// Writes (rows 4 apart) and reads (rows 1 apart) both land 2-way = free.
__device__ __forceinline__ int crow(int row) { return row * 112; }
__device__ __forceinline__ int cxor(int row) { return ((row >> 2) & 1) << 4; }

// grid: 256 blocks = bg(8) x gg(32); block: 512 threads = 8 waves
__global__ __launch_bounds__(512, 2) void lstm_persist(
    const float* __restrict__ rnn, const float* __restrict__ tau,
    const float* __restrict__ z0,  const float* __restrict__ c0,
    const float* __restrict__ wuw, const float* __restrict__ wub,
    const float* __restrict__ awp, const float* __restrict__ abp,
    const float* __restrict__ whw, const float* __restrict__ whb,
    const float* __restrict__ Amat, const float* __restrict__ Bmat,
    float* __restrict__ out, char* __restrict__ img)
{
  __shared__ float cscr[8 * 16 * 112];   // 56 KB, swizzled (gates 0..63, dots 64..67)
  __shared__ float gwL[4][16][4];        // per-unit x/u weights
  __shared__ float gbL[4][16];           // per-unit bias

  const int tid = threadIdx.x;
  const int blk = blockIdx.x;
  const int bg  = blk & 7;         // batch group -> rows [bg*32, bg*32+32)
  const int gg  = blk >> 3;        // gate group  -> units [gg*16, gg*16+16)
  const int rb0 = bg * 32;
  const int j0  = gg * 16;
  const int lane = tid & 63;
  const int wv   = tid >> 6;       // wave 0..7
  const int m    = wv & 1;         // M tile (16 rows)
  const int kq   = wv >> 1;        // K quarter (128)
  const int bb   = tid >> 4;       // 0..31 local batch row (pointwise mapping)
  const int jj   = tid & 15;       // unit-in-block
  const int gb   = rb0 + bb;
  const int ln15 = lane & 15;
  const int lq   = lane >> 4;

  // ---------------- prologue: weights -> registers (split f16) ----------------
  f16x8 bHf[4][5], bLf[4][5];
#pragma unroll
  for (int s = 0; s < 4; ++s) {
    const int kbase = kq * 128 + s * 32 + lq * 8;
#pragma unroll
    for (int n = 0; n < 4; ++n) {
      const float* wp = wuw + (size_t)(n * 512 + j0 + ln15) * WUC + 4 + kbase;
      f16x8 vh, vl;
#pragma unroll
      for (int e = 0; e < 8; ++e) {
        float w = wp[e];
        _Float16 hi = (_Float16)w;
        vh[e] = hi;
        vl[e] = (_Float16)(w - (float)hi);
      }
      bHf[s][n] = vh; bLf[s][n] = vl;
    }
    {
      f16x8 vh, vl;
#pragma unroll
      for (int e = 0; e < 8; ++e) {   // n=4: [alpha_w ; Wh_w ; zeros] tile
        int k = kbase + e;
        float w = 0.f;
        if (ln15 < 2)      w = awp[ln15 * 512 + k];
        else if (ln15 < 4) w = whw[(ln15 - 2) * 512 + k];
        _Float16 hi = (_Float16)w;
        vh[e] = hi;
        vl[e] = (_Float16)(w - (float)hi);
      }
      bHf[s][4] = vh; bLf[s][4] = vl;
    }
  }
  // small params
  const float pA00 = Amat[0], pA01 = Amat[1], pA10 = Amat[2], pA11 = Amat[3];
  const float pB0 = Bmat[0], pB1 = Bmat[1];
  const float pab0 = abp[0], pab1 = abp[1], pwb0 = whb[0], pwb1 = whb[1];
  if (tid < 64) {
    const int n = tid >> 4, j = tid & 15;
    const int r = n * 512 + j0 + j;
    gbL[n][j] = wub[r];
    const float* wr = wuw + (size_t)r * WUC;
    gwL[n][j][0] = wr[0]; gwL[n][j][1] = wr[1];
    gwL[n][j][2] = wr[2]; gwL[n][j][3] = wr[3];
  }
  // states (x replicated across the 16 threads of each bb-group)
  float px0 = z0[(size_t)gb * Z_ + 0], px1 = z0[(size_t)gb * Z_ + 1];
  float c_state = c0[(size_t)gb * Z_ + 2 + j0 + jj];
  float u0_prev = 0.f, tau_prev = 0.f, hval = 0.f;
  float alc0 = 0.f, alc1 = 0.f;

  // publish z0 h-slice into slot 3 ("h(-1)"), pair-packed fire-and-forget
  {
    float hv = z0[(size_t)gb * Z_ + 2 + j0 + jj];
    unsigned hz = (unsigned)__builtin_bit_cast(unsigned short, (_Float16)hv);
    unsigned ph = (unsigned)__shfl_xor((int)hz, 1);
    if ((jj & 1) == 0)
      st4c(img + (size_t)(3 * 8 + bg) * IMG_BYTES + bb * 1024 + (j0 + jj) * 2,
           hz | (ph << 16));
  }
  __syncthreads();

  const int fragbase = (m * 16 + ln15) * 1024 + kq * 256 + lq * 16;
  const int mm = bb >> 4, rr = bb & 15;

  // ---------------- main loop ----------------
  for (int t = 0; t < S_; ++t) {
    const float u0v = rnn[((size_t)gb * S_ + t) * 2 + 0];
    const float u1v = rnn[((size_t)gb * S_ + t) * 2 + 1];
    const float tv  = tau[(size_t)gb * S_ + t];

    // deferred harness stores — acks complete in the spin shadow
    if (t >= 1)
      __builtin_nontemporal_store(hval, out + ((size_t)gb * S_ + (t - 1)) * Z_ + 2 + j0 + jj);
    if (t >= 2 && gg == 0 && jj == 0) {
      const size_t ob = ((size_t)gb * S_ + (t - 2)) * Z_;
      __builtin_nontemporal_store(px0, out + ob + 0);
      __builtin_nontemporal_store(px1, out + ob + 1);
      const size_t cb = OUT_COEF + ((size_t)gb * S_ + (t - 2)) * 2;
      __builtin_nontemporal_store(alc0, out + cb + 0);
      __builtin_nontemporal_store(alc1, out + cb + 1);
    }

    // self-validating spin: the poll IS the fragment load (slot (t-1)&3).
    // RULE #18 FENCE: sched_barrier(0) after the vmcnt drain (round-6 proven).
    const char* baseR = img + (size_t)(((t + 3) & 3) * 8 + bg) * IMG_BYTES + fragbase;
    u32x4 A0, A1, A2, A3;
    {
      bool ok0 = false, ok1 = false, ok2 = false, ok3 = false;
      for (;;) {
        if (!ok0) A0 = ld16c(baseR + 0);
        if (!ok1) A1 = ld16c(baseR + 64);
        if (!ok2) A2 = ld16c(baseR + 128);
        if (!ok3) A3 = ld16c(baseR + 192);
        asm volatile("s_waitcnt vmcnt(0)" ::: "memory");
        __builtin_amdgcn_sched_barrier(0);
        ok0 = rdy(A0); ok1 = rdy(A1); ok2 = rdy(A2); ok3 = rdy(A3);
        if (ok0 && ok1 && ok2 && ok3) break;
        __builtin_amdgcn_s_sleep(1);
      }
    }
    __builtin_amdgcn_sched_barrier(0);

    // GEMM: split H/L accumulators -> 10 independent 4-deep MFMA chains
    f32x4 h0 = {0,0,0,0}, h1 = {0,0,0,0}, h2 = {0,0,0,0}, h3 = {0,0,0,0}, h4 = {0,0,0,0};
    f32x4 l0 = {0,0,0,0}, l1 = {0,0,0,0}, l2 = {0,0,0,0}, l3 = {0,0,0,0}, l4 = {0,0,0,0};
#pragma unroll
    for (int s = 0; s < 4; ++s) {
      u32x4 As = (s == 0) ? A0 : (s == 1) ? A1 : (s == 2) ? A2 : A3;
      f16x8 ah = __builtin_bit_cast(f16x8, As);
      h0 = MF16(ah, bHf[s][0], h0); l0 = MF16(ah, bLf[s][0], l0);
      h1 = MF16(ah, bHf[s][1], h1); l1 = MF16(ah, bLf[s][1], l1);
      h2 = MF16(ah, bHf[s][2], h2); l2 = MF16(ah, bLf[s][2], l2);
      h3 = MF16(ah, bHf[s][3], h3); l3 = MF16(ah, bLf[s][3], l3);
      h4 = MF16(ah, bHf[s][4], h4); l4 = MF16(ah, bLf[s][4], l4);
    }
    const f32x4 a0 = h0 + l0, a1 = h1 + l1, a2 = h2 + l2, a3 = h3 + l3, a4 = h4 + l4;
    {
      const int Rb = (kq * 2 + m) * 16 + lq * 4;
#pragma unroll
      for (int r = 0; r < 4; ++r) {
        const int row = Rb + r;
        float* cp = cscr + crow(row);
        const int xb = cxor(row);
        cp[(0 * 16 ^ xb) + ln15] = a0[r];
        cp[(1 * 16 ^ xb) + ln15] = a1[r];
        cp[(2 * 16 ^ xb) + ln15] = a2[r];
        cp[(3 * 16 ^ xb) + ln15] = a3[r];
        cp[(4 * 16 ^ xb) + ln15] = a4[r];
      }
    }
    __syncthreads();   // B1: LDS write->read (vmcnt already 0 from the spin)

    // gate sums + alpha/Wh dots (dot quad is one aligned float4)
    float g0 = 0, g1 = 0, g2 = 0, g3 = 0, d0 = 0, d1 = 0, d2 = 0, d3 = 0;
#pragma unroll
    for (int q = 0; q < 4; ++q) {
      const int row = (q * 2 + mm) * 16 + rr;
      const float* cp = cscr + crow(row);
      const int xb = cxor(row);
      g0 += cp[(0 * 16 ^ xb) + jj]; g1 += cp[(1 * 16 ^ xb) + jj];
      g2 += cp[(2 * 16 ^ xb) + jj]; g3 += cp[(3 * 16 ^ xb) + jj];
      const f32x4 dv = *(const f32x4*)(cp + (64 ^ xb));
      d0 += dv[0]; d1 += dv[1]; d2 += dv[2]; d3 += dv[3];
    }
    // finalize x(t-1) (replicated per-thread, uniform within each bb-group)
    if (t > 0) {
      const float al0 = sigm(d0 + pab0), al1 = sigm(d1 + pab1);
      const float wh0 = d2 + pwb0, wh1 = d3 + pwb1;
      const float xm0 = px0 + tau_prev * (pA00 * px0 + pA01 * px1 + pB0 * u0_prev);
      const float xm1 = px1 + tau_prev * (pA10 * px0 + pA11 * px1 + pB1 * u0_prev);
      px0 = al0 * xm0 + (1.f - al0) * wh0;
      px1 = al1 * xm1 + (1.f - al1) * wh1;
      alc0 = al0; alc1 = al1;
    }
    // pointwise LSTM
    g0 += gbL[0][jj] + px0 * gwL[0][jj][0] + px1 * gwL[0][jj][1] + u0v * gwL[0][jj][2] + u1v * gwL[0][jj][3];
    g1 += gbL[1][jj] + px0 * gwL[1][jj][0] + px1 * gwL[1][jj][1] + u0v * gwL[1][jj][2] + u1v * gwL[1][jj][3];
    g2 += gbL[2][jj] + px0 * gwL[2][jj][0] + px1 * gwL[2][jj][1] + u0v * gwL[2][jj][2] + u1v * gwL[2][jj][3];
    g3 += gbL[3][jj] + px0 * gwL[3][jj][0] + px1 * gwL[3][jj][1] + u0v * gwL[3][jj][2] + u1v * gwL[3][jj][3];
    const float ci = sigm(g0), cf = sigm(g1), co = sigm(g3);
    c_state = cf * c_state + ci * ftanh(g2);
    hval = co * ftanh(c_state);
    u0_prev = u0v; tau_prev = tv;

    // publish h(t) -> slot t&3: pair-packed 4B stores, fire-and-forget
    {
      unsigned hz = (unsigned)__builtin_bit_cast(unsigned short, (_Float16)hval);
      unsigned ph = (unsigned)__shfl_xor((int)hz, 1);
      if ((jj & 1) == 0)
        st4c(img + (size_t)((t & 3) * 8 + bg) * IMG_BYTES + bb * 1024 + (j0 + jj) * 2,
             hz | (ph << 16));
    }
    // wave 0 re-poisons this block's slice of slot (t+2)&3 (holds dead h(t-2)).
    // Visibility chain WITHOUT a B2 drain: poison is drained by wave 0's own
    // vmcnt(0) in its next spin, which precedes (via B1) this block's h(t+1)
    // publish, which precedes any block's h(t+2) publish into that slot.
    if (wv == 0) {
      const int row = lane >> 1, half = lane & 1;
      u32x4 poison = {~0u, ~0u, ~0u, ~0u};
      st16c(img + (size_t)(((t + 2) & 3) * 8 + bg) * IMG_BYTES + row * 1024 + (j0 + half * 8) * 2,
            poison);
    }
    // B2: raw barrier — drain LDS/shfl (lgkm, cheap) but NOT vmcnt: the publish
    // store ack retires inside the next spin's vmcnt(0), overlapped with the
    // wait for the other 31 producers.
    asm volatile("s_waitcnt lgkmcnt(0)" ::: "memory");
    __builtin_amdgcn_sched_barrier(0);
    __builtin_amdgcn_s_barrier();
    __builtin_amdgcn_sched_barrier(0);
  }

  // ---------------- tail: pending stores + alpha/x for t = 511 ----------------
  __builtin_nontemporal_store(hval, out + ((size_t)gb * S_ + 511) * Z_ + 2 + j0 + jj);
  __builtin_nontemporal_store(hval,    out + OUT_ZF  + (size_t)gb * Z_ + 2 + j0 + jj);
  __builtin_nontemporal_store(c_state, out + OUT_CZF + (size_t)gb * Z_ + 2 + j0 + jj);
  if (gg == 0 && jj == 0) {
    const size_t ob = ((size_t)gb * S_ + 510) * Z_;
    __builtin_nontemporal_store(px0, out + ob + 0);
    __builtin_nontemporal_store(px1, out + ob + 1);
    const size_t cb = OUT_COEF + ((size_t)gb * S_ + 510) * 2;
    __builtin_nontemporal_store(alc0, out + cb + 0);
    __builtin_nontemporal_store(alc1, out + cb + 1);
  }

  // final alpha/Wh GEMM over h(511) (slot 511&3 = 3), NaN-spin validated
  {
    const char* baseR = img + (size_t)(3 * 8 + bg) * IMG_BYTES + fragbase;
    u32x4 A0, A1, A2, A3;
    {
      bool ok0 = false, ok1 = false, ok2 = false, ok3 = false;
      for (;;) {
        if (!ok0) A0 = ld16c(baseR + 0);
        if (!ok1) A1 = ld16c(baseR + 64);
        if (!ok2) A2 = ld16c(baseR + 128);
        if (!ok3) A3 = ld16c(baseR + 192);
        asm volatile("s_waitcnt vmcnt(0)" ::: "memory");
        __builtin_amdgcn_sched_barrier(0);
        ok0 = rdy(A0); ok1 = rdy(A1); ok2 = rdy(A2); ok3 = rdy(A3);
        if (ok0 && ok1 && ok2 && ok3) break;
        __builtin_amdgcn_s_sleep(1);
      }
    }
    __builtin_amdgcn_sched_barrier(0);
    f32x4 h4 = {0,0,0,0}, l4 = {0,0,0,0};
#pragma unroll
    for (int s = 0; s < 4; ++s) {
      u32x4 As = (s == 0) ? A0 : (s == 1) ? A1 : (s == 2) ? A2 : A3;
      f16x8 ah = __builtin_bit_cast(f16x8, As);
      h4 = MF16(ah, bHf[s][4], h4); l4 = MF16(ah, bLf[s][4], l4);
    }
    const f32x4 a4 = h4 + l4;
    const int Rb = (kq * 2 + m) * 16 + lq * 4;
#pragma unroll
    for (int r = 0; r < 4; ++r) {
      const int row = Rb + r;
      cscr[crow(row) + ((4 * 16) ^ cxor(row)) + ln15] = a4[r];
    }
  }
  __syncthreads();
  {
    float d0 = 0, d1 = 0, d2 = 0, d3 = 0;
#pragma unroll
    for (int q = 0; q < 4; ++q) {
      const int row = (q * 2 + mm) * 16 + rr;
      const f32x4 dv = *(const f32x4*)(cscr + crow(row) + (64 ^ cxor(row)));
      d0 += dv[0]; d1 += dv[1]; d2 += dv[2]; d3 += dv[3];
    }
    const float al0 = sigm(d0 + pab0), al1 = sigm(d1 + pab1);
    const float wh0 = d2 + pwb0, wh1 = d3 + pwb1;
    const float xm0 = px0 + tau_prev * (pA00 * px0 + pA01 * px1 + pB0 * u0_prev);
    const float xm1 = px1 + tau_prev * (pA10 * px0 + pA11 * px1 + pB1 * u0_prev);
    const float xn0 = al0 * xm0 + (1.f - al0) * wh0;
    const float xn1 = al1 * xm1 + (1.f - al1) * wh1;
    if (gg == 0 && jj == 0) {
      const size_t ob = ((size_t)gb * S_ + 511) * Z_;
      __builtin_nontemporal_store(xn0, out + ob + 0);
      __builtin_nontemporal_store(xn1, out + ob + 1);
      const size_t cb = OUT_COEF + ((size_t)gb * S_ + 511) * 2;
      __builtin_nontemporal_store(al0, out + cb + 0);
      __builtin_nontemporal_store(al1, out + cb + 1);
      __builtin_nontemporal_store(xn0, out + OUT_ZF  + (size_t)gb * Z_ + 0);
      __builtin_nontemporal_store(xn1, out + OUT_ZF  + (size_t)gb * Z_ + 1);
      __builtin_nontemporal_store(c0[(size_t)gb * Z_ + 0], out + OUT_CZF + (size_t)gb * Z_ + 0);
      __builtin_nontemporal_store(c0[(size_t)gb * Z_ + 1], out + OUT_CZF + (size_t)gb * Z_ + 1);
    }
  }
}

extern "C" void kernel_launch(void* const* d_in, const int* in_sizes, int n_in,
                              void* d_out, int out_size, void* d_ws, size_t ws_size,
                              hipStream_t stream) {
  const float* rnn  = (const float*)d_in[0];
  const float* tauP = (const float*)d_in[1];
  const float* z0   = (const float*)d_in[2];
  const float* c0   = (const float*)d_in[3];
  const float* wuw  = (const float*)d_in[4];
  const float* wub  = (const float*)d_in[5];
  const float* awp  = (const float*)d_in[6];
  const float* abp  = (const float*)d_in[7];
  const float* whw  = (const float*)d_in[8];
  const float* whb  = (const float*)d_in[9];
  const float* Amat = (const float*)d_in[10];
  const float* Bmat = (const float*)d_in[11];
  float* out = (float*)d_out;
  char* img = (char*)d_ws;   // 1 MB: 4 slots x 8 bg x 32KB

  // poison all image slots (f16 NaN sentinel) every call — captured in the graph
  hipMemsetAsync(d_ws, 0xFF, 4 * 8 * IMG_BYTES, stream);
  (void)in_sizes; (void)n_in; (void)out_size; (void)ws_size;

  hipLaunchKernelGGL(lstm_persist, dim3(256), dim3(512), 0, stream,
                     rnn, tauP, z0, c0, wuw, wub, awp, abp, whw, whb, Amat, Bmat,
                     out, img);
}

// Round 10
// 1448.166 us; speedup vs baseline: 1.4042x; 1.2148x over previous
//
#include <hip/hip_runtime.h>
#include <cmath>

// ---------------- problem constants ----------------
#define S_   512
#define Z_   514            // SD + H
#define WUC  516            // WU_w cols: [x(2) | u(2) | h(512)]

// output float offsets
#define OUT_ZF   67371008   // B*S*Z
#define OUT_CZF  67502592   // + B*Z
#define OUT_COEF 67634176   // + B*Z

// ---------------- workspace layout ----------------
// img: [slot(4)][bg(8)] x 32KB f16 image [32 rows][512 units]; 1MB total.
// Launch-time memset 0xFF poisons everything (0xFFFF = f16 NaN sentinel;
// real h / z0-h are always finite, so sentinel is unambiguous).
#define IMG_BYTES 32768

typedef __attribute__((ext_vector_type(4))) float f32x4;
typedef __attribute__((ext_vector_type(4))) unsigned u32x4;
typedef __attribute__((ext_vector_type(8))) _Float16 f16x8;

__device__ __forceinline__ f32x4 MF16(f16x8 a, f16x8 b, f32x4 c) {
  return __builtin_amdgcn_mfma_f32_16x16x32_f16(a, b, c, 0, 0, 0);
}
// system-scope (sc0 sc1) coherent ops — round-2/4/6-proven encoding
__device__ __forceinline__ u32x4 ld16c(const void* p) {
  u32x4 r;
  asm volatile("global_load_dwordx4 %0, %1, off sc0 sc1" : "=v"(r) : "v"(p));
  return r;
}
__device__ __forceinline__ void st16c(void* p, u32x4 v) {
  asm volatile("global_store_dwordx4 %0, %1, off sc0 sc1" :: "v"(p), "v"(v) : "memory");
}
__device__ __forceinline__ void st4c(void* p, unsigned v) {
  asm volatile("global_store_dword %0, %1, off sc0 sc1" :: "v"(p), "v"(v) : "memory");
}
// chunk ready: no dword still holds the poison pattern in its low half
// (producer 4B stores are dword-atomic: each dword is all-poison or all-data)
__device__ __forceinline__ bool rdy(u32x4 v) {
  unsigned b = (unsigned)((v[0] & 0xFFFFu) == 0xFFFFu) |
               (unsigned)((v[1] & 0xFFFFu) == 0xFFFFu) |
               (unsigned)((v[2] & 0xFFFFu) == 0xFFFFu) |
               (unsigned)((v[3] & 0xFFFFu) == 0xFFFFu);
  return b == 0u;
}
// overflow-safe fast transcendentals (inf-graceful, no NaN paths)
__device__ __forceinline__ float sigm(float x)  { return 1.f / (1.f + __expf(-x)); }
__device__ __forceinline__ float ftanh(float x) { return 2.f / (1.f + __expf(-2.f * x)) - 1.f; }

// cscr swizzled index: stride 112 floats, XOR bit4 of col with (row>>2)&1.
// Writes (rows 4 apart) and reads (rows 1 apart) both land 2-way = free.
__device__ __forceinline__ int crow(int row) { return row * 112; }
__device__ __forceinline__ int cxor(int row) { return ((row >> 2) & 1) << 4; }

// grid: 256 blocks = bg(8) x gg(32); block: 512 threads = 8 waves
__global__ __launch_bounds__(512, 2) void lstm_persist(
    const float* __restrict__ rnn, const float* __restrict__ tau,
    const float* __restrict__ z0,  const float* __restrict__ c0,
    const float* __restrict__ wuw, const float* __restrict__ wub,
    const float* __restrict__ awp, const float* __restrict__ abp,
    const float* __restrict__ whw, const float* __restrict__ whb,
    const float* __restrict__ Amat, const float* __restrict__ Bmat,
    float* __restrict__ out, char* __restrict__ img)
{
  __shared__ float cscr[8 * 16 * 112];   // 56 KB, swizzled (gates 0..63, dots 64..67)
  __shared__ float gwL[4][16][4];        // per-unit x/u weights
  __shared__ float gbL[4][16];           // per-unit bias

  const int tid = threadIdx.x;
  const int blk = blockIdx.x;
  const int bg  = blk & 7;         // batch group -> rows [bg*32, bg*32+32)
  const int gg  = blk >> 3;        // gate group  -> units [gg*16, gg*16+16)
  const int rb0 = bg * 32;
  const int j0  = gg * 16;
  const int lane = tid & 63;
  const int wv   = tid >> 6;       // wave 0..7
  const int m    = wv & 1;         // M tile (16 rows)
  const int kq   = wv >> 1;        // K quarter (128)
  const int bb   = tid >> 4;       // 0..31 local batch row (pointwise mapping)
  const int jj   = tid & 15;       // unit-in-block
  const int gb   = rb0 + bb;
  const int ln15 = lane & 15;
  const int lq   = lane >> 4;

  // ---------------- prologue: weights -> registers (split f16) ----------------
  f16x8 bHf[4][5], bLf[4][5];
#pragma unroll
  for (int s = 0; s < 4; ++s) {
    const int kbase = kq * 128 + s * 32 + lq * 8;
#pragma unroll
    for (int n = 0; n < 4; ++n) {
      const float* wp = wuw + (size_t)(n * 512 + j0 + ln15) * WUC + 4 + kbase;
      f16x8 vh, vl;
#pragma unroll
      for (int e = 0; e < 8; ++e) {
        float w = wp[e];
        _Float16 hi = (_Float16)w;
        vh[e] = hi;
        vl[e] = (_Float16)(w - (float)hi);
      }
      bHf[s][n] = vh; bLf[s][n] = vl;
    }
    {
      f16x8 vh, vl;
#pragma unroll
      for (int e = 0; e < 8; ++e) {   // n=4: [alpha_w ; Wh_w ; zeros] tile
        int k = kbase + e;
        float w = 0.f;
        if (ln15 < 2)      w = awp[ln15 * 512 + k];
        else if (ln15 < 4) w = whw[(ln15 - 2) * 512 + k];
        _Float16 hi = (_Float16)w;
        vh[e] = hi;
        vl[e] = (_Float16)(w - (float)hi);
      }
      bHf[s][4] = vh; bLf[s][4] = vl;
    }
  }
  // small params
  const float pA00 = Amat[0], pA01 = Amat[1], pA10 = Amat[2], pA11 = Amat[3];
  const float pB0 = Bmat[0], pB1 = Bmat[1];
  const float pab0 = abp[0], pab1 = abp[1], pwb0 = whb[0], pwb1 = whb[1];
  if (tid < 64) {
    const int n = tid >> 4, j = tid & 15;
    const int r = n * 512 + j0 + j;
    gbL[n][j] = wub[r];
    const float* wr = wuw + (size_t)r * WUC;
    gwL[n][j][0] = wr[0]; gwL[n][j][1] = wr[1];
    gwL[n][j][2] = wr[2]; gwL[n][j][3] = wr[3];
  }
  // states (x replicated across the 16 threads of each bb-group)
  float px0 = z0[(size_t)gb * Z_ + 0], px1 = z0[(size_t)gb * Z_ + 1];
  float c_state = c0[(size_t)gb * Z_ + 2 + j0 + jj];
  float u0_prev = 0.f, tau_prev = 0.f, hval = 0.f;
  float alc0 = 0.f, alc1 = 0.f;

  // publish z0 h-slice into slot 3 ("h(-1)"), pair-packed fire-and-forget
  {
    float hv = z0[(size_t)gb * Z_ + 2 + j0 + jj];
    unsigned hz = (unsigned)__builtin_bit_cast(unsigned short, (_Float16)hv);
    unsigned ph = (unsigned)__shfl_xor((int)hz, 1);
    if ((jj & 1) == 0)
      st4c(img + (size_t)(3 * 8 + bg) * IMG_BYTES + bb * 1024 + (j0 + jj) * 2,
           hz | (ph << 16));
  }
  __syncthreads();

  const int fragbase = (m * 16 + ln15) * 1024 + kq * 256 + lq * 16;
  const int mm = bb >> 4, rr = bb & 15;

  // ---------------- main loop ----------------
  for (int t = 0; t < S_; ++t) {
    const float u0v = rnn[((size_t)gb * S_ + t) * 2 + 0];
    const float u1v = rnn[((size_t)gb * S_ + t) * 2 + 1];
    const float tv  = tau[(size_t)gb * S_ + t];

    // deferred harness stores — acks complete in the spin shadow
    if (t >= 1)
      __builtin_nontemporal_store(hval, out + ((size_t)gb * S_ + (t - 1)) * Z_ + 2 + j0 + jj);
    if (t >= 2 && gg == 0 && jj == 0) {
      const size_t ob = ((size_t)gb * S_ + (t - 2)) * Z_;
      __builtin_nontemporal_store(px0, out + ob + 0);
      __builtin_nontemporal_store(px1, out + ob + 1);
      const size_t cb = OUT_COEF + ((size_t)gb * S_ + (t - 2)) * 2;
      __builtin_nontemporal_store(alc0, out + cb + 0);
      __builtin_nontemporal_store(alc1, out + cb + 1);
    }

    // self-validating spin: the poll IS the fragment load (slot (t-1)&3).
    // RULE #18 FENCE: sched_barrier(0) after the vmcnt drain, else the compiler
    // schedules the register-only rdy() checks BEFORE the waitcnt (reading the
    // load destination regs before the load completes) -> garbage passes -> NaN.
    const char* baseR = img + (size_t)(((t + 3) & 3) * 8 + bg) * IMG_BYTES + fragbase;
    u32x4 A0, A1, A2, A3;
    {
      bool ok0 = false, ok1 = false, ok2 = false, ok3 = false;
      for (;;) {
        if (!ok0) A0 = ld16c(baseR + 0);
        if (!ok1) A1 = ld16c(baseR + 64);
        if (!ok2) A2 = ld16c(baseR + 128);
        if (!ok3) A3 = ld16c(baseR + 192);
        asm volatile("s_waitcnt vmcnt(0)" ::: "memory");
        __builtin_amdgcn_sched_barrier(0);
        ok0 = rdy(A0); ok1 = rdy(A1); ok2 = rdy(A2); ok3 = rdy(A3);
        if (ok0 && ok1 && ok2 && ok3) break;
        __builtin_amdgcn_s_sleep(1);
      }
    }
    __builtin_amdgcn_sched_barrier(0);

    f32x4 a0 = {0,0,0,0}, a1 = {0,0,0,0}, a2 = {0,0,0,0}, a3 = {0,0,0,0}, a4 = {0,0,0,0};
#pragma unroll
    for (int s = 0; s < 4; ++s) {
      u32x4 As = (s == 0) ? A0 : (s == 1) ? A1 : (s == 2) ? A2 : A3;
      f16x8 ah = __builtin_bit_cast(f16x8, As);
      a0 = MF16(ah, bHf[s][0], a0); a0 = MF16(ah, bLf[s][0], a0);
      a1 = MF16(ah, bHf[s][1], a1); a1 = MF16(ah, bLf[s][1], a1);
      a2 = MF16(ah, bHf[s][2], a2); a2 = MF16(ah, bLf[s][2], a2);
      a3 = MF16(ah, bHf[s][3], a3); a3 = MF16(ah, bLf[s][3], a3);
      a4 = MF16(ah, bHf[s][4], a4); a4 = MF16(ah, bLf[s][4], a4);
    }
    {
      const int Rb = (kq * 2 + m) * 16 + lq * 4;
#pragma unroll
      for (int r = 0; r < 4; ++r) {
        const int row = Rb + r;
        float* cp = cscr + crow(row);
        const int xb = cxor(row);
        cp[(0 * 16 ^ xb) + ln15] = a0[r];
        cp[(1 * 16 ^ xb) + ln15] = a1[r];
        cp[(2 * 16 ^ xb) + ln15] = a2[r];
        cp[(3 * 16 ^ xb) + ln15] = a3[r];
        cp[(4 * 16 ^ xb) + ln15] = a4[r];
      }
    }
    __syncthreads();   // B1

    // gate sums + alpha/Wh dots (dot quad is one aligned float4)
    float g0 = 0, g1 = 0, g2 = 0, g3 = 0, d0 = 0, d1 = 0, d2 = 0, d3 = 0;
#pragma unroll
    for (int q = 0; q < 4; ++q) {
      const int row = (q * 2 + mm) * 16 + rr;
      const float* cp = cscr + crow(row);
      const int xb = cxor(row);
      g0 += cp[(0 * 16 ^ xb) + jj]; g1 += cp[(1 * 16 ^ xb) + jj];
      g2 += cp[(2 * 16 ^ xb) + jj]; g3 += cp[(3 * 16 ^ xb) + jj];
      const f32x4 dv = *(const f32x4*)(cp + (64 ^ xb));
      d0 += dv[0]; d1 += dv[1]; d2 += dv[2]; d3 += dv[3];
    }
    // finalize x(t-1) (replicated per-thread, uniform within each bb-group)
    if (t > 0) {
      const float al0 = sigm(d0 + pab0), al1 = sigm(d1 + pab1);
      const float wh0 = d2 + pwb0, wh1 = d3 + pwb1;
      const float xm0 = px0 + tau_prev * (pA00 * px0 + pA01 * px1 + pB0 * u0_prev);
      const float xm1 = px1 + tau_prev * (pA10 * px0 + pA11 * px1 + pB1 * u0_prev);
      px0 = al0 * xm0 + (1.f - al0) * wh0;
      px1 = al1 * xm1 + (1.f - al1) * wh1;
      alc0 = al0; alc1 = al1;
    }
    // pointwise LSTM
    g0 += gbL[0][jj] + px0 * gwL[0][jj][0] + px1 * gwL[0][jj][1] + u0v * gwL[0][jj][2] + u1v * gwL[0][jj][3];
    g1 += gbL[1][jj] + px0 * gwL[1][jj][0] + px1 * gwL[1][jj][1] + u0v * gwL[1][jj][2] + u1v * gwL[1][jj][3];
    g2 += gbL[2][jj] + px0 * gwL[2][jj][0] + px1 * gwL[2][jj][1] + u0v * gwL[2][jj][2] + u1v * gwL[2][jj][3];
    g3 += gbL[3][jj] + px0 * gwL[3][jj][0] + px1 * gwL[3][jj][1] + u0v * gwL[3][jj][2] + u1v * gwL[3][jj][3];
    const float ci = sigm(g0), cf = sigm(g1), co = sigm(g3);
    c_state = cf * c_state + ci * ftanh(g2);
    hval = co * ftanh(c_state);
    u0_prev = u0v; tau_prev = tv;

    // publish h(t) -> slot t&3: pair-packed 4B stores, fire-and-forget
    {
      unsigned hz = (unsigned)__builtin_bit_cast(unsigned short, (_Float16)hval);
      unsigned ph = (unsigned)__shfl_xor((int)hz, 1);
      if ((jj & 1) == 0)
        st4c(img + (size_t)((t & 3) * 8 + bg) * IMG_BYTES + bb * 1024 + (j0 + jj) * 2,
             hz | (ph << 16));
    }
    // wave 0 re-poisons this block's slice of slot (t+2)&3 (holds dead h(t-2);
    // drained by wave 0's next spin vmcnt(0), ordered before t+2's publish by B1)
    if (wv == 0) {
      const int row = lane >> 1, half = lane & 1;
      u32x4 poison = {~0u, ~0u, ~0u, ~0u};
      st16c(img + (size_t)(((t + 2) & 3) * 8 + bg) * IMG_BYTES + row * 1024 + (j0 + half * 8) * 2,
            poison);
    }
    __syncthreads();   // B2: full drain — the producer self-throttle that keeps
                       // the 32-block group phase-locked (R7/R8/R9: removing it
                       // costs ~+300us in consumer retries)
  }

  // ---------------- tail: pending stores + alpha/x for t = 511 ----------------
  __builtin_nontemporal_store(hval, out + ((size_t)gb * S_ + 511) * Z_ + 2 + j0 + jj);
  __builtin_nontemporal_store(hval,    out + OUT_ZF  + (size_t)gb * Z_ + 2 + j0 + jj);
  __builtin_nontemporal_store(c_state, out + OUT_CZF + (size_t)gb * Z_ + 2 + j0 + jj);
  if (gg == 0 && jj == 0) {
    const size_t ob = ((size_t)gb * S_ + 510) * Z_;
    __builtin_nontemporal_store(px0, out + ob + 0);
    __builtin_nontemporal_store(px1, out + ob + 1);
    const size_t cb = OUT_COEF + ((size_t)gb * S_ + 510) * 2;
    __builtin_nontemporal_store(alc0, out + cb + 0);
    __builtin_nontemporal_store(alc1, out + cb + 1);
  }

  // final alpha/Wh GEMM over h(511) (slot 511&3 = 3), NaN-spin validated
  {
    const char* baseR = img + (size_t)(3 * 8 + bg) * IMG_BYTES + fragbase;
    u32x4 A0, A1, A2, A3;
    {
      bool ok0 = false, ok1 = false, ok2 = false, ok3 = false;
      for (;;) {
        if (!ok0) A0 = ld16c(baseR + 0);
        if (!ok1) A1 = ld16c(baseR + 64);
        if (!ok2) A2 = ld16c(baseR + 128);
        if (!ok3) A3 = ld16c(baseR + 192);
        asm volatile("s_waitcnt vmcnt(0)" ::: "memory");
        __builtin_amdgcn_sched_barrier(0);
        ok0 = rdy(A0); ok1 = rdy(A1); ok2 = rdy(A2); ok3 = rdy(A3);
        if (ok0 && ok1 && ok2 && ok3) break;
        __builtin_amdgcn_s_sleep(1);
      }
    }
    __builtin_amdgcn_sched_barrier(0);
    f32x4 a4 = {0,0,0,0};
#pragma unroll
    for (int s = 0; s < 4; ++s) {
      u32x4 As = (s == 0) ? A0 : (s == 1) ? A1 : (s == 2) ? A2 : A3;
      f16x8 ah = __builtin_bit_cast(f16x8, As);
      a4 = MF16(ah, bHf[s][4], a4); a4 = MF16(ah, bLf[s][4], a4);
    }
    const int Rb = (kq * 2 + m) * 16 + lq * 4;
#pragma unroll
    for (int r = 0; r < 4; ++r) {
      const int row = Rb + r;
      cscr[crow(row) + ((4 * 16) ^ cxor(row)) + ln15] = a4[r];
    }
  }
  __syncthreads();
  {
    float d0 = 0, d1 = 0, d2 = 0, d3 = 0;
#pragma unroll
    for (int q = 0; q < 4; ++q) {
      const int row = (q * 2 + mm) * 16 + rr;
      const f32x4 dv = *(const f32x4*)(cscr + crow(row) + (64 ^ cxor(row)));
      d0 += dv[0]; d1 += dv[1]; d2 += dv[2]; d3 += dv[3];
    }
    const float al0 = sigm(d0 + pab0), al1 = sigm(d1 + pab1);
    const float wh0 = d2 + pwb0, wh1 = d3 + pwb1;
    const float xm0 = px0 + tau_prev * (pA00 * px0 + pA01 * px1 + pB0 * u0_prev);
    const float xm1 = px1 + tau_prev * (pA10 * px0 + pA11 * px1 + pB1 * u0_prev);
    const float xn0 = al0 * xm0 + (1.f - al0) * wh0;
    const float xn1 = al1 * xm1 + (1.f - al1) * wh1;
    if (gg == 0 && jj == 0) {
      const size_t ob = ((size_t)gb * S_ + 511) * Z_;
      __builtin_nontemporal_store(xn0, out + ob + 0);
      __builtin_nontemporal_store(xn1, out + ob + 1);
      const size_t cb = OUT_COEF + ((size_t)gb * S_ + 511) * 2;
      __builtin_nontemporal_store(al0, out + cb + 0);
      __builtin_nontemporal_store(al1, out + cb + 1);
      __builtin_nontemporal_store(xn0, out + OUT_ZF  + (size_t)gb * Z_ + 0);
      __builtin_nontemporal_store(xn1, out + OUT_ZF  + (size_t)gb * Z_ + 1);
      __builtin_nontemporal_store(c0[(size_t)gb * Z_ + 0], out + OUT_CZF + (size_t)gb * Z_ + 0);
      __builtin_nontemporal_store(c0[(size_t)gb * Z_ + 1], out + OUT_CZF + (size_t)gb * Z_ + 1);
    }
  }
}

extern "C" void kernel_launch(void* const* d_in, const int* in_sizes, int n_in,
                              void* d_out, int out_size, void* d_ws, size_t ws_size,
                              hipStream_t stream) {
  const float* rnn  = (const float*)d_in[0];
  const float* tauP = (const float*)d_in[1];
  const float* z0   = (const float*)d_in[2];
  const float* c0   = (const float*)d_in[3];
  const float* wuw  = (const float*)d_in[4];
  const float* wub  = (const float*)d_in[5];
  const float* awp  = (const float*)d_in[6];
  const float* abp  = (const float*)d_in[7];
  const float* whw  = (const float*)d_in[8];
  const float* whb  = (const float*)d_in[9];
  const float* Amat = (const float*)d_in[10];
  const float* Bmat = (const float*)d_in[11];
  float* out = (float*)d_out;
  char* img = (char*)d_ws;   // 1 MB: 4 slots x 8 bg x 32KB

  // poison all image slots to 0xFFFF (f16 NaN sentinel) every call — part of the
  // captured graph, so every replay starts from the identical poisoned state
  hipMemsetAsync(d_ws, 0xFF, 4 * 8 * IMG_BYTES, stream);
  (void)in_sizes; (void)n_in; (void)out_size; (void)ws_size;

  hipLaunchKernelGGL(lstm_persist, dim3(256), dim3(512), 0, stream,
                     rnn, tauP, z0, c0, wuw, wub, awp, abp, whw, whb, Amat, Bmat,
                     out, img);
}